// Round 4
// baseline (317.018 us; speedup 1.0000x reference)
//
#include <hip/hip_runtime.h>

#define B_ 4
#define SQ_ 2048
#define SKV_ 2048
#define E_ 1024
#define H_ 16
#define D_ 64

typedef __bf16 bf16x8 __attribute__((ext_vector_type(8)));
typedef __bf16 bf16x4 __attribute__((ext_vector_type(4)));
typedef float f32x4 __attribute__((ext_vector_type(4)));
typedef short short4v __attribute__((ext_vector_type(4)));

__device__ inline f32x4 zero4() { f32x4 z = {0.f, 0.f, 0.f, 0.f}; return z; }

// Convert 8 consecutive f32 (32B-aligned) to a bf16x8 MFMA fragment.
__device__ inline bf16x8 cvt8(const float* __restrict__ p) {
    const float4 a = ((const float4*)p)[0];
    const float4 b = ((const float4*)p)[1];
    bf16x8 r;
    r[0] = (__bf16)a.x; r[1] = (__bf16)a.y; r[2] = (__bf16)a.z; r[3] = (__bf16)a.w;
    r[4] = (__bf16)b.x; r[5] = (__bf16)b.y; r[6] = (__bf16)b.z; r[7] = (__bf16)b.w;
    return r;
}

#define MFMA16(a, b, c) __builtin_amdgcn_mfma_f32_16x16x32_bf16(a, b, c, 0, 0, 0)

// exp(score/8) = 2^(score * 0.125 * log2(e)); folded into qh at projection.
#define QSCALE 0.18033688011112042f

// async global->LDS, 16B per lane; LDS dest is wave-uniform base + lane*16.
__device__ inline void stage16(const __bf16* g, __bf16* l) {
    __builtin_amdgcn_global_load_lds(
        (const __attribute__((address_space(1))) void*)g,
        (__attribute__((address_space(3))) void*)l, 16, 0, 0);
}

// ---------------------------------------------------------------------------
__global__ __launch_bounds__(256) void cast_wo_kernel(const float* __restrict__ wo,
                                                      __bf16* __restrict__ wo_bf) {
    int i = (blockIdx.x * 256 + threadIdx.x) * 4;
    float4 v = *(const float4*)(wo + i);
    wo_bf[i + 0] = (__bf16)v.x;
    wo_bf[i + 1] = (__bf16)v.y;
    wo_bf[i + 2] = (__bf16)v.z;
    wo_bf[i + 3] = (__bf16)v.w;
}

// ---------------------------------------------------------------------------
// Q projection (scaled by QSCALE for exp2-based softmax).
// v2: results staged through an LDS tile so global stores are coalesced
// 16B vectors (was: 16 scalar 2B stores/thread in scattered 32B row-runs).
__global__ __launch_bounds__(256) void proj_q_kernel(const float* __restrict__ q,
                                                     const float* __restrict__ wq,
                                                     const float* __restrict__ bq,
                                                     __bf16* __restrict__ qh) {
    __shared__ __bf16 tile[64 * 72];        // [row t 0..63][col d 0..63], pad 72
    const int w = threadIdx.x >> 6, lane = threadIdx.x & 63;
    const int l15 = lane & 15, quad = lane >> 4;
    const int b = blockIdx.z, h = blockIdx.y;
    const int s_blk = blockIdx.x * 64;
    const int s_base = s_blk + w * 16;

    const float* qrow = q + ((size_t)b * SQ_ + s_base + l15) * E_ + h * D_ + quad * 8;
    bf16x8 a0 = cvt8(qrow);
    bf16x8 a1 = cvt8(qrow + 32);

    f32x4 acc[4] = {zero4(), zero4(), zero4(), zero4()};
#pragma unroll
    for (int nb = 0; nb < 4; ++nb) {
        const float* wrow = wq + (size_t)h * D_ * D_ + (nb * 16 + l15) * D_ + quad * 8;
        bf16x8 b0 = cvt8(wrow);
        bf16x8 b1 = cvt8(wrow + 32);
        acc[nb] = MFMA16(a0, b0, acc[nb]);
        acc[nb] = MFMA16(a1, b1, acc[nb]);
    }

#pragma unroll
    for (int nb = 0; nb < 4; ++nb) {
        const int col = nb * 16 + l15;
        const float bias = bq[h * D_ + col];
#pragma unroll
        for (int r = 0; r < 4; ++r) {
            tile[(w * 16 + quad * 4 + r) * 72 + col] =
                (__bf16)((acc[nb][r] + bias) * QSCALE);
        }
    }
    __syncthreads();

    // cooperative coalesced store: 512 x 16B segments, consecutive tid ->
    // consecutive global addresses.
    __bf16* obase = qh + ((size_t)(b * H_ + h) * SQ_ + s_blk) * D_;
    const int tid = threadIdx.x;
#pragma unroll
    for (int i = 0; i < 2; ++i) {
        const int seg = i * 256 + tid;
        const int row = seg >> 3, sg = seg & 7;
        bf16x8 v = *(const bf16x8*)&tile[row * 72 + sg * 8];
        *(bf16x8*)&obase[(size_t)row * D_ + sg * 8] = v;
    }
}

// ---------------------------------------------------------------------------
// KV projection. Tile layouts for LDS staging in attention:
//   kh: per 64-row tile, element (t,d) at col chunk (d>>3)^(t&7)  [rows t].
//   vh: V TRANSPOSED per tile: [d=64 rows][t=64 cols], element (d,t) at
//       col chunk (t>>3)^(d&7). Both 8 KB contiguous per 64-kv tile.
// v2: both swizzled tiles assembled in LDS, then written to global as
// coalesced 16B vectors (was: 32 scalar 2B swizzle-scattered stores/thread).
__global__ __launch_bounds__(256) void proj_kv_kernel(const float* __restrict__ kv,
                                                      const float* __restrict__ wk,
                                                      const float* __restrict__ bk,
                                                      const float* __restrict__ wv,
                                                      const float* __restrict__ bv,
                                                      __bf16* __restrict__ kh,
                                                      __bf16* __restrict__ vh) {
    __shared__ __bf16 ktile[64 * 72];       // rows t, swizzled d-cols
    __shared__ __bf16 vtile[64 * 72];       // rows d, swizzled t-cols
    const int w = threadIdx.x >> 6, lane = threadIdx.x & 63;
    const int l15 = lane & 15, quad = lane >> 4;
    const int b = blockIdx.z, h = blockIdx.y;
    const int t_base = blockIdx.x * 64 + w * 16;

    const float* xrow = kv + ((size_t)b * SKV_ + t_base + l15) * E_ + h * D_ + quad * 8;
    bf16x8 a0 = cvt8(xrow);
    bf16x8 a1 = cvt8(xrow + 32);

    f32x4 acck[4] = {zero4(), zero4(), zero4(), zero4()};
    f32x4 accv[4] = {zero4(), zero4(), zero4(), zero4()};
#pragma unroll
    for (int nb = 0; nb < 4; ++nb) {
        const float* wkrow = wk + (size_t)h * D_ * D_ + (nb * 16 + l15) * D_ + quad * 8;
        const float* wvrow = wv + (size_t)h * D_ * D_ + (nb * 16 + l15) * D_ + quad * 8;
        bf16x8 bk0 = cvt8(wkrow);
        bf16x8 bk1 = cvt8(wkrow + 32);
        bf16x8 bv0 = cvt8(wvrow);
        bf16x8 bv1 = cvt8(wvrow + 32);
        acck[nb] = MFMA16(a0, bk0, acck[nb]);
        acck[nb] = MFMA16(a1, bk1, acck[nb]);
        accv[nb] = MFMA16(a0, bv0, accv[nb]);
        accv[nb] = MFMA16(a1, bv1, accv[nb]);
    }

#pragma unroll
    for (int nb = 0; nb < 4; ++nb) {
        const int col = nb * 16 + l15;  // head-dim d
        const float biask = bk[h * D_ + col];
        const float biasv = bv[h * D_ + col];
#pragma unroll
        for (int r = 0; r < 4; ++r) {
            const int row = quad * 4 + r;        // t within wave's 16-row slab
            const int tl = w * 16 + row;         // tile-local t
            // K: swizzle col chunk by t&7 (== row&7 since w*16 = 0 mod 8)
            const int kcol = (((col >> 3) ^ (row & 7)) << 3) | (col & 7);
            ktile[tl * 72 + kcol] = (__bf16)(acck[nb][r] + biask);
            // V^T: row d=col, col t=tl; chunk swizzled by d&7.
            const int vcol = (((tl >> 3) ^ (col & 7)) << 3) | (tl & 7);
            vtile[col * 72 + vcol] = (__bf16)(accv[nb][r] + biasv);
        }
    }
    __syncthreads();

    const int bh = b * H_ + h;
    __bf16* kbase = kh + ((size_t)bh * SKV_ + blockIdx.x * 64) * D_;
    __bf16* vbase = vh + (((size_t)bh * (SKV_ / 64) + blockIdx.x) * 64) * 64;
    const int tid = threadIdx.x;
#pragma unroll
    for (int i = 0; i < 2; ++i) {
        const int seg = i * 256 + tid;
        const int row = seg >> 3, sg = seg & 7;
        bf16x8 kv8 = *(const bf16x8*)&ktile[row * 72 + sg * 8];
        *(bf16x8*)&kbase[(size_t)row * D_ + sg * 8] = kv8;
        bf16x8 vv8 = *(const bf16x8*)&vtile[row * 72 + sg * 8];
        *(bf16x8*)&vbase[(size_t)row * 64 + sg * 8] = vv8;
    }
}

// ---------------------------------------------------------------------------
// Attention v6 (R1 best, reverted): K=32 register-direct PV, MFMA row-sums.
//   S^T = K·Q^T via MFMA(A=K-frag, B=Q-frag): C-layout col = q = lane&15.
//   P^T = exp2(S^T) feeds PV DIRECTLY from registers at K=32: MFMA contracts
//   slot-aligned, so any t-permutation works as long as A and B agree. The
//   B-operand packs two 16-row P blocks (slots j<4 <- nb=2a, j>=4 <- nb=2a+1);
//   the V^T A-operand reads the SAME permuted layout from LDS.
//   Row sums via MFMA against a ones A-operand.
// Block = 256 q-rows (4 waves x 64 rows = 4 q-tiles each). K/V 64x64 tiles
// staged per block via global_load_lds, double-buffered, 1 barrier/tile.
// Grid 1-D 512: f = tq*64 + g, g=b*16+h -> all tiles of one (b,h) on one XCD.
__global__ __launch_bounds__(256, 2) void attn_kernel(const __bf16* __restrict__ qh,
                                                      const __bf16* __restrict__ kh,
                                                      const __bf16* __restrict__ vh,
                                                      __bf16* __restrict__ ctx) {
    __shared__ __bf16 k_lds[2][4096];       // 64 t-rows x 64 d (swizzled)
    __shared__ __bf16 v_lds[2][4096];       // 64 d-rows x 64 t (swizzled)
    __shared__ __bf16 t_lds[4][16][72];     // per-wave epilogue transpose

    const int w = threadIdx.x >> 6, lane = threadIdx.x & 63;
    const int l15 = lane & 15, quad = lane >> 4;
    const int f = blockIdx.x;
    const int g = f & 63, tq = f >> 6;
    const int b = g >> 4, h = g & 15;
    const int bh = b * H_ + h;
    const int s_base = tq * 256 + w * 64;
    const int sw8 = (l15 & 7) << 3;

    bf16x8 aq[4][2];
#pragma unroll
    for (int qt = 0; qt < 4; ++qt) {
        const __bf16* qb = qh + ((size_t)bh * SQ_ + s_base + qt * 16 + l15) * D_ + quad * 8;
        aq[qt][0] = *(const bf16x8*)qb;
        aq[qt][1] = *(const bf16x8*)(qb + 32);
    }

    const __bf16 one_bf = (__bf16)1.0f;
    bf16x8 ones;
#pragma unroll
    for (int j = 0; j < 8; ++j) ones[j] = one_bf;

    f32x4 oT[4][4];   // [qt][d-block], C-layout: col=q=lane&15, row=d=quad*4+r
    f32x4 lacc[4];    // row-sum accumulator per qt; all rows identical
#pragma unroll
    for (int qt = 0; qt < 4; ++qt) {
        lacc[qt] = zero4();
#pragma unroll
        for (int db = 0; db < 4; ++db) oT[qt][db] = zero4();
    }

    const __bf16* kt = kh + (size_t)bh * SKV_ * D_;
    const __bf16* vt = vh + (size_t)bh * SKV_ * D_;

    auto stage = [&](int buf, int it) {
#pragma unroll
        for (int c2 = 0; c2 < 2; ++c2) {
            const int c = w + c2 * 4;
            stage16(kt + (size_t)it * 4096 + c * 512 + lane * 8, &k_lds[buf][c * 512]);
            stage16(vt + (size_t)it * 4096 + c * 512 + lane * 8, &v_lds[buf][c * 512]);
        }
    };

    stage(0, 0);
    __syncthreads();

    for (int it = 0; it < SKV_ / 64; ++it) {
        const int cur = it & 1;
        if (it + 1 < SKV_ / 64) stage(cur ^ 1, it + 1);

        // K fragments (A-operand of S^T): lane = t, k = d = quad*8+j
        bf16x8 kf0[4], kf1[4];
#pragma unroll
        for (int nb = 0; nb < 4; ++nb) {
            const __bf16* kr = &k_lds[cur][(nb * 16 + l15) * 64];
            kf0[nb] = *(const bf16x8*)&kr[(quad << 3) ^ sw8];
            kf1[nb] = *(const bf16x8*)&kr[((quad + 4) << 3) ^ sw8];
        }
        // V^T fragments (A-operand of PV, K=32 permuted-slot layout):
        // lane = d; slot(quad,j) = t = 32a + (j>=4)*16 + quad*4 + (j&3)
        bf16x8 vtf[4][2];
#pragma unroll
        for (int db = 0; db < 4; ++db) {
            const __bf16* vr = &v_lds[cur][(db * 16 + l15) * 64];
#pragma unroll
            for (int a = 0; a < 2; ++a) {
                const int c_lo = a * 4 + (quad >> 1);
                const int lo_off = (((c_lo ^ (l15 & 7)) << 3) | ((quad & 1) * 4));
                const int hi_off = ((((c_lo + 2) ^ (l15 & 7)) << 3) | ((quad & 1) * 4));
                union { bf16x8 v8; bf16x4 h2[2]; } u;
                u.h2[0] = *(const bf16x4*)&vr[lo_off];
                u.h2[1] = *(const bf16x4*)&vr[hi_off];
                vtf[db][a] = u.v8;
            }
        }
        // per q-tile: S^T -> exp -> PV (register-direct, K=32)
#pragma unroll
        for (int qt = 0; qt < 4; ++qt) {
            f32x4 s[4] = {zero4(), zero4(), zero4(), zero4()};
#pragma unroll
            for (int nb = 0; nb < 4; ++nb) {
                s[nb] = MFMA16(kf0[nb], aq[qt][0], s[nb]);
                s[nb] = MFMA16(kf1[nb], aq[qt][1], s[nb]);
            }
            // pack P^T into two K=32 B-fragments (slot-permuted, matches vtf)
            bf16x8 pb[2];
#pragma unroll
            for (int a = 0; a < 2; ++a) {
#pragma unroll
                for (int hf = 0; hf < 2; ++hf) {
                    const int nb = a * 2 + hf;
                    pb[a][hf * 4 + 0] = (__bf16)__builtin_amdgcn_exp2f(s[nb][0]);
                    pb[a][hf * 4 + 1] = (__bf16)__builtin_amdgcn_exp2f(s[nb][1]);
                    pb[a][hf * 4 + 2] = (__bf16)__builtin_amdgcn_exp2f(s[nb][2]);
                    pb[a][hf * 4 + 3] = (__bf16)__builtin_amdgcn_exp2f(s[nb][3]);
                }
            }
            // row sums via ones-MFMA: lacc cols=q, fully reduced over 64 t
            lacc[qt] = MFMA16(ones, pb[0], lacc[qt]);
            lacc[qt] = MFMA16(ones, pb[1], lacc[qt]);
#pragma unroll
            for (int db = 0; db < 4; ++db)
#pragma unroll
                for (int a = 0; a < 2; ++a)
                    oT[qt][db] = MFMA16(vtf[db][a], pb[a], oT[qt][db]);
        }
        __syncthreads();
    }

    // epilogue: scale by 1/l (lacc[qt][0] = denominator for q=lane&15),
    // transpose via LDS, store
#pragma unroll
    for (int qt = 0; qt < 4; ++qt) {
        const float inv = 1.f / lacc[qt][0];
#pragma unroll
        for (int db = 0; db < 4; ++db) {
#pragma unroll
            for (int r = 0; r < 4; ++r) {
                t_lds[w][l15][db * 16 + quad * 4 + r] = (__bf16)(oT[qt][db][r] * inv);
            }
        }
        // same-wave read-back (no barrier): 8 lanes per q-row, 16B stores
#pragma unroll
        for (int pp = 0; pp < 2; ++pp) {
            const int row = (lane >> 3) + pp * 8;
            bf16x8 vrow = *(const bf16x8*)&t_lds[w][row][(lane & 7) * 8];
            *(bf16x8*)&ctx[((size_t)b * SQ_ + s_base + qt * 16 + row) * E_ + h * D_ +
                           (lane & 7) * 8] = vrow;
        }
    }
}

// ---------------------------------------------------------------------------
// Output GEMM: out[m,n] = sum_k ctx[m,k] * wo[n,k] + bo[n]
// M=8192, N=1024, K=1024. v2: wave tile 32x64 (was 64x64), grid 1024 ->
// 4 blocks/CU / 4 waves/SIMD. Theory: the 1-deep prefetch can't hide VMEM
// latency (32 MFMA = 155 cyc < 200-900 cyc load latency) at 2 waves/SIMD;
// doubling resident waves overlaps the per-iteration stall across waves.
// f = nblk*64 + mblk; XCD = mblk%8: per-XCD working set = all B (2MB) +
// 8 A-panels (2MB) -> fits 4MB L2.
__global__ __launch_bounds__(256, 4) void ogemm_kernel(const __bf16* __restrict__ ctx,
                                                       const __bf16* __restrict__ wo_bf,
                                                       const float* __restrict__ bo,
                                                       float* __restrict__ out) {
    const int w = threadIdx.x >> 6, lane = threadIdx.x & 63;
    const int l15 = lane & 15, quad = lane >> 4;
    const int f = blockIdx.x;
    const int mblk = f & 63, nblk = f >> 6;
    const int m_base = mblk * 128 + w * 32;
    const int n_base = nblk * 64;

    f32x4 acc[2][4];
#pragma unroll
    for (int sub = 0; sub < 2; ++sub)
#pragma unroll
        for (int nb = 0; nb < 4; ++nb) acc[sub][nb] = zero4();

    const __bf16* arow = ctx + (size_t)(m_base + l15) * E_ + quad * 8;
    const __bf16* brow = wo_bf + (size_t)(n_base + l15) * E_ + quad * 8;

    bf16x8 a[2], bb[4];
#pragma unroll
    for (int sub = 0; sub < 2; ++sub) a[sub] = *(const bf16x8*)(arow + (size_t)sub * 16 * E_);
#pragma unroll
    for (int nb = 0; nb < 4; ++nb) bb[nb] = *(const bf16x8*)(brow + (size_t)nb * 16 * E_);

    for (int kk = 0; kk < E_; kk += 64) {
        bf16x8 an[2], bbn[4];
#pragma unroll
        for (int sub = 0; sub < 2; ++sub)
            an[sub] = *(const bf16x8*)(arow + (size_t)sub * 16 * E_ + kk + 32);
#pragma unroll
        for (int nb = 0; nb < 4; ++nb)
            bbn[nb] = *(const bf16x8*)(brow + (size_t)nb * 16 * E_ + kk + 32);
#pragma unroll
        for (int nb = 0; nb < 4; ++nb)
#pragma unroll
            for (int sub = 0; sub < 2; ++sub)
                acc[sub][nb] = MFMA16(a[sub], bb[nb], acc[sub][nb]);
        const int k2 = (kk + 64) & (E_ - 1);
#pragma unroll
        for (int sub = 0; sub < 2; ++sub)
            a[sub] = *(const bf16x8*)(arow + (size_t)sub * 16 * E_ + k2);
#pragma unroll
        for (int nb = 0; nb < 4; ++nb)
            bb[nb] = *(const bf16x8*)(brow + (size_t)nb * 16 * E_ + k2);
#pragma unroll
        for (int nb = 0; nb < 4; ++nb)
#pragma unroll
            for (int sub = 0; sub < 2; ++sub)
                acc[sub][nb] = MFMA16(an[sub], bbn[nb], acc[sub][nb]);
    }

#pragma unroll
    for (int sub = 0; sub < 2; ++sub) {
#pragma unroll
        for (int nb = 0; nb < 4; ++nb) {
            const int col = n_base + nb * 16 + l15;
            const float bias = bo[col];
#pragma unroll
            for (int r = 0; r < 4; ++r) {
                const int row = m_base + sub * 16 + quad * 4 + r;
                out[(size_t)row * E_ + col] = acc[sub][nb][r] + bias;
            }
        }
    }
}

// ---------------------------------------------------------------------------
extern "C" void kernel_launch(void* const* d_in, const int* in_sizes, int n_in,
                              void* d_out, int out_size, void* d_ws, size_t ws_size,
                              hipStream_t stream) {
    const float* query = (const float*)d_in[0];
    const float* key_value = (const float*)d_in[1];
    const float* wq = (const float*)d_in[2];
    const float* bq = (const float*)d_in[3];
    const float* wk = (const float*)d_in[4];
    const float* bk = (const float*)d_in[5];
    const float* wv = (const float*)d_in[6];
    const float* bv = (const float*)d_in[7];
    const float* wo = (const float*)d_in[8];
    const float* bo = (const float*)d_in[9];
    float* out = (float*)d_out;

    // workspace layout (needs 66 MB): qh | kh | vh | ctx | wo_bf
    char* ws = (char*)d_ws;
    __bf16* qh = (__bf16*)(ws);                         // 16 MB [B,H,SQ,D]
    __bf16* kh = (__bf16*)(ws + (16u << 20));           // 16 MB swizzled K tiles
    __bf16* vh = (__bf16*)(ws + (32u << 20));           // 16 MB swizzled V^T tiles
    __bf16* ctxb = (__bf16*)(ws + (48u << 20));         // 16 MB [B,SQ,E]
    __bf16* wo_bf = (__bf16*)(ws + (64u << 20));        // 2 MB  [E,E]

    hipLaunchKernelGGL(cast_wo_kernel, dim3(E_ * E_ / 1024), dim3(256), 0, stream, wo, wo_bf);
    hipLaunchKernelGGL(proj_q_kernel, dim3(SQ_ / 64, H_, B_), dim3(256), 0, stream,
                       query, wq, bq, qh);
    hipLaunchKernelGGL(proj_kv_kernel, dim3(SKV_ / 64, H_, B_), dim3(256), 0, stream,
                       key_value, wk, bk, wv, bv, kh, vh);
    hipLaunchKernelGGL(attn_kernel, dim3(B_ * H_ * (SQ_ / 256)), dim3(256), 0, stream,
                       qh, kh, vh, ctxb);
    hipLaunchKernelGGL(ogemm_kernel, dim3((B_ * SQ_ / 128) * (E_ / 64)), dim3(256), 0, stream,
                       ctxb, wo_bf, bo, out);
}

// Round 5
// 253.583 us; speedup vs baseline: 1.2502x; 1.2502x over previous
//
#include <hip/hip_runtime.h>

#define B_ 4
#define SQ_ 2048
#define SKV_ 2048
#define E_ 1024
#define H_ 16
#define D_ 64

typedef __bf16 bf16x8 __attribute__((ext_vector_type(8)));
typedef __bf16 bf16x4 __attribute__((ext_vector_type(4)));
typedef float f32x4 __attribute__((ext_vector_type(4)));

__device__ inline f32x4 zero4() { f32x4 z = {0.f, 0.f, 0.f, 0.f}; return z; }

// Convert 8 consecutive f32 (32B-aligned) to a bf16x8 MFMA fragment.
__device__ inline bf16x8 cvt8(const float* __restrict__ p) {
    const float4 a = ((const float4*)p)[0];
    const float4 b = ((const float4*)p)[1];
    bf16x8 r;
    r[0] = (__bf16)a.x; r[1] = (__bf16)a.y; r[2] = (__bf16)a.z; r[3] = (__bf16)a.w;
    r[4] = (__bf16)b.x; r[5] = (__bf16)b.y; r[6] = (__bf16)b.z; r[7] = (__bf16)b.w;
    return r;
}

#define MFMA16(a, b, c) __builtin_amdgcn_mfma_f32_16x16x32_bf16(a, b, c, 0, 0, 0)

// exp(score/8) = 2^(score * 0.125 * log2(e)); folded into qh at projection.
#define QSCALE 0.18033688011112042f

// async global->LDS, 16B per lane; LDS dest is wave-uniform base + lane*16.
__device__ inline void stage16(const __bf16* g, __bf16* l) {
    __builtin_amdgcn_global_load_lds(
        (const __attribute__((address_space(1))) void*)g,
        (__attribute__((address_space(3))) void*)l, 16, 0, 0);
}

// ---------------------------------------------------------------------------
__global__ __launch_bounds__(256) void cast_wo_kernel(const float* __restrict__ wo,
                                                      __bf16* __restrict__ wo_bf) {
    int i = (blockIdx.x * 256 + threadIdx.x) * 4;
    float4 v = *(const float4*)(wo + i);
    wo_bf[i + 0] = (__bf16)v.x;
    wo_bf[i + 1] = (__bf16)v.y;
    wo_bf[i + 2] = (__bf16)v.z;
    wo_bf[i + 3] = (__bf16)v.w;
}

// ---------------------------------------------------------------------------
// Q projection (scaled by QSCALE for exp2-based softmax).
// Results staged through an LDS tile so global stores are coalesced 16B.
__global__ __launch_bounds__(256) void proj_q_kernel(const float* __restrict__ q,
                                                     const float* __restrict__ wq,
                                                     const float* __restrict__ bq,
                                                     __bf16* __restrict__ qh) {
    __shared__ __bf16 tile[64 * 72];        // [row t 0..63][col d 0..63], pad 72
    const int w = threadIdx.x >> 6, lane = threadIdx.x & 63;
    const int l15 = lane & 15, quad = lane >> 4;
    const int b = blockIdx.z, h = blockIdx.y;
    const int s_blk = blockIdx.x * 64;
    const int s_base = s_blk + w * 16;

    const float* qrow = q + ((size_t)b * SQ_ + s_base + l15) * E_ + h * D_ + quad * 8;
    bf16x8 a0 = cvt8(qrow);
    bf16x8 a1 = cvt8(qrow + 32);

    f32x4 acc[4] = {zero4(), zero4(), zero4(), zero4()};
#pragma unroll
    for (int nb = 0; nb < 4; ++nb) {
        const float* wrow = wq + (size_t)h * D_ * D_ + (nb * 16 + l15) * D_ + quad * 8;
        bf16x8 b0 = cvt8(wrow);
        bf16x8 b1 = cvt8(wrow + 32);
        acc[nb] = MFMA16(a0, b0, acc[nb]);
        acc[nb] = MFMA16(a1, b1, acc[nb]);
    }

#pragma unroll
    for (int nb = 0; nb < 4; ++nb) {
        const int col = nb * 16 + l15;
        const float bias = bq[h * D_ + col];
#pragma unroll
        for (int r = 0; r < 4; ++r) {
            tile[(w * 16 + quad * 4 + r) * 72 + col] =
                (__bf16)((acc[nb][r] + bias) * QSCALE);
        }
    }
    __syncthreads();

    // cooperative coalesced store: 512 x 16B segments.
    __bf16* obase = qh + ((size_t)(b * H_ + h) * SQ_ + s_blk) * D_;
    const int tid = threadIdx.x;
#pragma unroll
    for (int i = 0; i < 2; ++i) {
        const int seg = i * 256 + tid;
        const int row = seg >> 3, sg = seg & 7;
        bf16x8 v = *(const bf16x8*)&tile[row * 72 + sg * 8];
        *(bf16x8*)&obase[(size_t)row * D_ + sg * 8] = v;
    }
}

// ---------------------------------------------------------------------------
// KV projection. Tile layouts for LDS staging in attention:
//   kh: per 64-row tile, element (t,d) at col chunk (d>>3)^(t&7)  [rows t].
//   vh: V TRANSPOSED per tile: [d=64 rows][t=64 cols], element (d,t) at
//       col chunk (t>>3)^(d&7). Both 8 KB contiguous per 64-kv tile.
// Both swizzled tiles assembled in LDS, then written coalesced 16B.
__global__ __launch_bounds__(256) void proj_kv_kernel(const float* __restrict__ kv,
                                                      const float* __restrict__ wk,
                                                      const float* __restrict__ bk,
                                                      const float* __restrict__ wv,
                                                      const float* __restrict__ bv,
                                                      __bf16* __restrict__ kh,
                                                      __bf16* __restrict__ vh) {
    __shared__ __bf16 ktile[64 * 72];       // rows t, swizzled d-cols
    __shared__ __bf16 vtile[64 * 72];       // rows d, swizzled t-cols
    const int w = threadIdx.x >> 6, lane = threadIdx.x & 63;
    const int l15 = lane & 15, quad = lane >> 4;
    const int b = blockIdx.z, h = blockIdx.y;
    const int t_base = blockIdx.x * 64 + w * 16;

    const float* xrow = kv + ((size_t)b * SKV_ + t_base + l15) * E_ + h * D_ + quad * 8;
    bf16x8 a0 = cvt8(xrow);
    bf16x8 a1 = cvt8(xrow + 32);

    f32x4 acck[4] = {zero4(), zero4(), zero4(), zero4()};
    f32x4 accv[4] = {zero4(), zero4(), zero4(), zero4()};
#pragma unroll
    for (int nb = 0; nb < 4; ++nb) {
        const float* wkrow = wk + (size_t)h * D_ * D_ + (nb * 16 + l15) * D_ + quad * 8;
        const float* wvrow = wv + (size_t)h * D_ * D_ + (nb * 16 + l15) * D_ + quad * 8;
        bf16x8 bk0 = cvt8(wkrow);
        bf16x8 bk1 = cvt8(wkrow + 32);
        bf16x8 bv0 = cvt8(wvrow);
        bf16x8 bv1 = cvt8(wvrow + 32);
        acck[nb] = MFMA16(a0, bk0, acck[nb]);
        acck[nb] = MFMA16(a1, bk1, acck[nb]);
        accv[nb] = MFMA16(a0, bv0, accv[nb]);
        accv[nb] = MFMA16(a1, bv1, accv[nb]);
    }

#pragma unroll
    for (int nb = 0; nb < 4; ++nb) {
        const int col = nb * 16 + l15;  // head-dim d
        const float biask = bk[h * D_ + col];
        const float biasv = bv[h * D_ + col];
#pragma unroll
        for (int r = 0; r < 4; ++r) {
            const int row = quad * 4 + r;        // t within wave's 16-row slab
            const int tl = w * 16 + row;         // tile-local t
            // K: swizzle col chunk by t&7 (== row&7 since w*16 = 0 mod 8)
            const int kcol = (((col >> 3) ^ (row & 7)) << 3) | (col & 7);
            ktile[tl * 72 + kcol] = (__bf16)(acck[nb][r] + biask);
            // V^T: row d=col, col t=tl; chunk swizzled by d&7.
            const int vcol = (((tl >> 3) ^ (col & 7)) << 3) | (tl & 7);
            vtile[col * 72 + vcol] = (__bf16)(accv[nb][r] + biasv);
        }
    }
    __syncthreads();

    const int bh = b * H_ + h;
    __bf16* kbase = kh + ((size_t)bh * SKV_ + blockIdx.x * 64) * D_;
    __bf16* vbase = vh + (((size_t)bh * (SKV_ / 64) + blockIdx.x) * 64) * 64;
    const int tid = threadIdx.x;
#pragma unroll
    for (int i = 0; i < 2; ++i) {
        const int seg = i * 256 + tid;
        const int row = seg >> 3, sg = seg & 7;
        bf16x8 kv8 = *(const bf16x8*)&ktile[row * 72 + sg * 8];
        *(bf16x8*)&kbase[(size_t)row * D_ + sg * 8] = kv8;
        bf16x8 vv8 = *(const bf16x8*)&vtile[row * 72 + sg * 8];
        *(bf16x8*)&vbase[(size_t)row * 64 + sg * 8] = vv8;
    }
}

// ---------------------------------------------------------------------------
// Attention v6 (R1 best): K=32 register-direct PV, MFMA row-sums.
//   S^T = K·Q^T via MFMA(A=K-frag, B=Q-frag): C-layout col = q = lane&15.
//   P^T = exp2(S^T) feeds PV DIRECTLY from registers at K=32 (slot-aligned
//   permutation shared by the V^T A-operand). Row sums via ones-MFMA.
// Block = 256 q-rows (4 waves x 64 rows = 4 q-tiles each). K/V 64x64 tiles
// staged per block via global_load_lds, double-buffered, 1 barrier/tile.
// Grid 1-D 512: f = tq*64 + g, g=b*16+h -> all tiles of one (b,h) on one XCD.
__global__ __launch_bounds__(256, 2) void attn_kernel(const __bf16* __restrict__ qh,
                                                      const __bf16* __restrict__ kh,
                                                      const __bf16* __restrict__ vh,
                                                      __bf16* __restrict__ ctx) {
    __shared__ __bf16 k_lds[2][4096];       // 64 t-rows x 64 d (swizzled)
    __shared__ __bf16 v_lds[2][4096];       // 64 d-rows x 64 t (swizzled)
    __shared__ __bf16 t_lds[4][16][72];     // per-wave epilogue transpose

    const int w = threadIdx.x >> 6, lane = threadIdx.x & 63;
    const int l15 = lane & 15, quad = lane >> 4;
    const int f = blockIdx.x;
    const int g = f & 63, tq = f >> 6;
    const int b = g >> 4, h = g & 15;
    const int bh = b * H_ + h;
    const int s_base = tq * 256 + w * 64;
    const int sw8 = (l15 & 7) << 3;

    bf16x8 aq[4][2];
#pragma unroll
    for (int qt = 0; qt < 4; ++qt) {
        const __bf16* qb = qh + ((size_t)bh * SQ_ + s_base + qt * 16 + l15) * D_ + quad * 8;
        aq[qt][0] = *(const bf16x8*)qb;
        aq[qt][1] = *(const bf16x8*)(qb + 32);
    }

    const __bf16 one_bf = (__bf16)1.0f;
    bf16x8 ones;
#pragma unroll
    for (int j = 0; j < 8; ++j) ones[j] = one_bf;

    f32x4 oT[4][4];   // [qt][d-block], C-layout: col=q=lane&15, row=d=quad*4+r
    f32x4 lacc[4];    // row-sum accumulator per qt; all rows identical
#pragma unroll
    for (int qt = 0; qt < 4; ++qt) {
        lacc[qt] = zero4();
#pragma unroll
        for (int db = 0; db < 4; ++db) oT[qt][db] = zero4();
    }

    const __bf16* kt = kh + (size_t)bh * SKV_ * D_;
    const __bf16* vt = vh + (size_t)bh * SKV_ * D_;

    auto stage = [&](int buf, int it) {
#pragma unroll
        for (int c2 = 0; c2 < 2; ++c2) {
            const int c = w + c2 * 4;
            stage16(kt + (size_t)it * 4096 + c * 512 + lane * 8, &k_lds[buf][c * 512]);
            stage16(vt + (size_t)it * 4096 + c * 512 + lane * 8, &v_lds[buf][c * 512]);
        }
    };

    stage(0, 0);
    __syncthreads();

    for (int it = 0; it < SKV_ / 64; ++it) {
        const int cur = it & 1;
        if (it + 1 < SKV_ / 64) stage(cur ^ 1, it + 1);

        // K fragments (A-operand of S^T): lane = t, k = d = quad*8+j
        bf16x8 kf0[4], kf1[4];
#pragma unroll
        for (int nb = 0; nb < 4; ++nb) {
            const __bf16* kr = &k_lds[cur][(nb * 16 + l15) * 64];
            kf0[nb] = *(const bf16x8*)&kr[(quad << 3) ^ sw8];
            kf1[nb] = *(const bf16x8*)&kr[((quad + 4) << 3) ^ sw8];
        }
        // V^T fragments (A-operand of PV, K=32 permuted-slot layout):
        // lane = d; slot(quad,j) = t = 32a + (j>=4)*16 + quad*4 + (j&3)
        bf16x8 vtf[4][2];
#pragma unroll
        for (int db = 0; db < 4; ++db) {
            const __bf16* vr = &v_lds[cur][(db * 16 + l15) * 64];
#pragma unroll
            for (int a = 0; a < 2; ++a) {
                const int c_lo = a * 4 + (quad >> 1);
                const int lo_off = (((c_lo ^ (l15 & 7)) << 3) | ((quad & 1) * 4));
                const int hi_off = ((((c_lo + 2) ^ (l15 & 7)) << 3) | ((quad & 1) * 4));
                union { bf16x8 v8; bf16x4 h2[2]; } u;
                u.h2[0] = *(const bf16x4*)&vr[lo_off];
                u.h2[1] = *(const bf16x4*)&vr[hi_off];
                vtf[db][a] = u.v8;
            }
        }
        // per q-tile: S^T -> exp -> PV (register-direct, K=32)
#pragma unroll
        for (int qt = 0; qt < 4; ++qt) {
            f32x4 s[4] = {zero4(), zero4(), zero4(), zero4()};
#pragma unroll
            for (int nb = 0; nb < 4; ++nb) {
                s[nb] = MFMA16(kf0[nb], aq[qt][0], s[nb]);
                s[nb] = MFMA16(kf1[nb], aq[qt][1], s[nb]);
            }
            // pack P^T into two K=32 B-fragments (slot-permuted, matches vtf)
            bf16x8 pb[2];
#pragma unroll
            for (int a = 0; a < 2; ++a) {
#pragma unroll
                for (int hf = 0; hf < 2; ++hf) {
                    const int nb = a * 2 + hf;
                    pb[a][hf * 4 + 0] = (__bf16)__builtin_amdgcn_exp2f(s[nb][0]);
                    pb[a][hf * 4 + 1] = (__bf16)__builtin_amdgcn_exp2f(s[nb][1]);
                    pb[a][hf * 4 + 2] = (__bf16)__builtin_amdgcn_exp2f(s[nb][2]);
                    pb[a][hf * 4 + 3] = (__bf16)__builtin_amdgcn_exp2f(s[nb][3]);
                }
            }
            // row sums via ones-MFMA: lacc cols=q, fully reduced over 64 t
            lacc[qt] = MFMA16(ones, pb[0], lacc[qt]);
            lacc[qt] = MFMA16(ones, pb[1], lacc[qt]);
#pragma unroll
            for (int db = 0; db < 4; ++db)
#pragma unroll
                for (int a = 0; a < 2; ++a)
                    oT[qt][db] = MFMA16(vtf[db][a], pb[a], oT[qt][db]);
        }
        __syncthreads();
    }

    // epilogue: scale by 1/l (lacc[qt][0] = denominator for q=lane&15),
    // transpose via LDS, store
#pragma unroll
    for (int qt = 0; qt < 4; ++qt) {
        const float inv = 1.f / lacc[qt][0];
#pragma unroll
        for (int db = 0; db < 4; ++db) {
#pragma unroll
            for (int r = 0; r < 4; ++r) {
                t_lds[w][l15][db * 16 + quad * 4 + r] = (__bf16)(oT[qt][db][r] * inv);
            }
        }
        // same-wave read-back (no barrier): 8 lanes per q-row, 16B stores
#pragma unroll
        for (int pp = 0; pp < 2; ++pp) {
            const int row = (lane >> 3) + pp * 8;
            bf16x8 vrow = *(const bf16x8*)&t_lds[w][row][(lane & 7) * 8];
            *(bf16x8*)&ctx[((size_t)b * SQ_ + s_base + qt * 16 + row) * E_ + h * D_ +
                           (lane & 7) * 8] = vrow;
        }
    }
}

// ---------------------------------------------------------------------------
// Output GEMM v3 (m97 structure): out[m,n] = sum_k ctx[m,k]*wo[n,k] + bo[n]
// M=8192, N=1024, K=1024. R4 counters showed the register-direct version is
// VMEM-latency bound (MfmaUtil 7%, VALUBusy 4%, HBM 7%): 8 MFMA per load
// round vs 200-900 cyc latency. v3: 128x128 block tile, BK=64, 4 waves x
// 64x64, A/B staged via global_load_lds (16B) into double-buffered LDS
// (64 KB, 2 blocks/CU), ds_read_b128 fragments. Chunk-XOR swizzle applied
// on the GLOBAL source address (LDS dest stays linear - gload_lds rule),
// reads XOR back -> conflict-free. 2-barrier K-loop, same machinery as attn.
// Grid 512: f = nblk*64 + mblk -> XCD = mblk%8: A-panel L2-resident per XCD
// (reused by 8 nblks), B (2 MB) fully L2-resident per XCD.
__global__ __launch_bounds__(256, 2) void ogemm_kernel(const __bf16* __restrict__ ctx,
                                                       const __bf16* __restrict__ wo_bf,
                                                       const float* __restrict__ bo,
                                                       float* __restrict__ out) {
    __shared__ __bf16 a_lds[2][8192];   // [128 m][8 chunks of 8 k-elems] swz
    __shared__ __bf16 b_lds[2][8192];   // [128 n][...] swz

    const int w = threadIdx.x >> 6, lane = threadIdx.x & 63;
    const int l15 = lane & 15, quad = lane >> 4;
    const int f = blockIdx.x;
    const int mblk = f & 63, nblk = f >> 6;
    const int m0 = mblk * 128, n0 = nblk * 128;
    const int wm = (w >> 1) * 64, wn = (w & 1) * 64;

    f32x4 acc[4][4];
#pragma unroll
    for (int sub = 0; sub < 4; ++sub)
#pragma unroll
        for (int nb = 0; nb < 4; ++nb) acc[sub][nb] = zero4();

    // staging: chunk c = w*4+i covers rows c*8..c*8+7 (8 lanes/row, 16B each).
    // stored[r][col8] = global[r][col8 ^ (r&7)]  (source pre-swizzled).
    const int sr = lane >> 3, sc = lane & 7;
    auto stage = [&](int buf, int kk) {
#pragma unroll
        for (int i = 0; i < 4; ++i) {
            const int c = w * 4 + i;
            const int r = c * 8 + sr;
            const int col8 = sc ^ (r & 7);
            stage16(ctx + (size_t)(m0 + r) * E_ + kk + col8 * 8, &a_lds[buf][c * 512]);
            stage16(wo_bf + (size_t)(n0 + r) * E_ + kk + col8 * 8, &b_lds[buf][c * 512]);
        }
    };

    stage(0, 0);
    __syncthreads();

    for (int it = 0; it < E_ / 64; ++it) {
        const int cur = it & 1;
        if (it + 1 < E_ / 64) stage(cur ^ 1, (it + 1) * 64);

#pragma unroll
        for (int h = 0; h < 2; ++h) {           // two K=32 halves of BK=64
            bf16x8 af[4], bf[4];
            const int cq = ((h * 4 + quad) ^ (l15 & 7)) * 8;
#pragma unroll
            for (int sub = 0; sub < 4; ++sub)
                af[sub] = *(const bf16x8*)&a_lds[cur][(wm + sub * 16 + l15) * 64 + cq];
#pragma unroll
            for (int nb = 0; nb < 4; ++nb)
                bf[nb] = *(const bf16x8*)&b_lds[cur][(wn + nb * 16 + l15) * 64 + cq];
#pragma unroll
            for (int nb = 0; nb < 4; ++nb)
#pragma unroll
                for (int sub = 0; sub < 4; ++sub)
                    acc[sub][nb] = MFMA16(af[sub], bf[nb], acc[sub][nb]);
        }
        __syncthreads();
    }

#pragma unroll
    for (int sub = 0; sub < 4; ++sub) {
#pragma unroll
        for (int nb = 0; nb < 4; ++nb) {
            const int col = n0 + wn + nb * 16 + l15;
            const float bias = bo[col];
#pragma unroll
            for (int r = 0; r < 4; ++r) {
                const int row = m0 + wm + sub * 16 + quad * 4 + r;
                out[(size_t)row * E_ + col] = acc[sub][nb][r] + bias;
            }
        }
    }
}

// ---------------------------------------------------------------------------
extern "C" void kernel_launch(void* const* d_in, const int* in_sizes, int n_in,
                              void* d_out, int out_size, void* d_ws, size_t ws_size,
                              hipStream_t stream) {
    const float* query = (const float*)d_in[0];
    const float* key_value = (const float*)d_in[1];
    const float* wq = (const float*)d_in[2];
    const float* bq = (const float*)d_in[3];
    const float* wk = (const float*)d_in[4];
    const float* bk = (const float*)d_in[5];
    const float* wv = (const float*)d_in[6];
    const float* bv = (const float*)d_in[7];
    const float* wo = (const float*)d_in[8];
    const float* bo = (const float*)d_in[9];
    float* out = (float*)d_out;

    // workspace layout (needs 66 MB): qh | kh | vh | ctx | wo_bf
    char* ws = (char*)d_ws;
    __bf16* qh = (__bf16*)(ws);                         // 16 MB [B,H,SQ,D]
    __bf16* kh = (__bf16*)(ws + (16u << 20));           // 16 MB swizzled K tiles
    __bf16* vh = (__bf16*)(ws + (32u << 20));           // 16 MB swizzled V^T tiles
    __bf16* ctxb = (__bf16*)(ws + (48u << 20));         // 16 MB [B,SQ,E]
    __bf16* wo_bf = (__bf16*)(ws + (64u << 20));        // 2 MB  [E,E]

    hipLaunchKernelGGL(cast_wo_kernel, dim3(E_ * E_ / 1024), dim3(256), 0, stream, wo, wo_bf);
    hipLaunchKernelGGL(proj_q_kernel, dim3(SQ_ / 64, H_, B_), dim3(256), 0, stream,
                       query, wq, bq, qh);
    hipLaunchKernelGGL(proj_kv_kernel, dim3(SKV_ / 64, H_, B_), dim3(256), 0, stream,
                       key_value, wk, bk, wv, bv, kh, vh);
    hipLaunchKernelGGL(attn_kernel, dim3(B_ * H_ * (SQ_ / 256)), dim3(256), 0, stream,
                       qh, kh, vh, ctxb);
    hipLaunchKernelGGL(ogemm_kernel, dim3((B_ * SQ_ / 128) * (E_ / 128)), dim3(256), 0, stream,
                       ctxb, wo_bf, bo, out);
}

// Round 6
// 234.164 us; speedup vs baseline: 1.3538x; 1.0829x over previous
//
#include <hip/hip_runtime.h>

#define B_ 4
#define SQ_ 2048
#define SKV_ 2048
#define E_ 1024
#define H_ 16
#define D_ 64

typedef __bf16 bf16x8 __attribute__((ext_vector_type(8)));
typedef __bf16 bf16x4 __attribute__((ext_vector_type(4)));
typedef float f32x4 __attribute__((ext_vector_type(4)));

__device__ inline f32x4 zero4() { f32x4 z = {0.f, 0.f, 0.f, 0.f}; return z; }

// Convert 8 consecutive f32 (32B-aligned) to a bf16x8 MFMA fragment.
__device__ inline bf16x8 cvt8(const float* __restrict__ p) {
    const float4 a = ((const float4*)p)[0];
    const float4 b = ((const float4*)p)[1];
    bf16x8 r;
    r[0] = (__bf16)a.x; r[1] = (__bf16)a.y; r[2] = (__bf16)a.z; r[3] = (__bf16)a.w;
    r[4] = (__bf16)b.x; r[5] = (__bf16)b.y; r[6] = (__bf16)b.z; r[7] = (__bf16)b.w;
    return r;
}

#define MFMA16(a, b, c) __builtin_amdgcn_mfma_f32_16x16x32_bf16(a, b, c, 0, 0, 0)

// exp(score/8) = 2^(score * 0.125 * log2(e)); folded into Q at projection.
#define QSCALE 0.18033688011112042f

// async global->LDS, 16B per lane; LDS dest is wave-uniform base + lane*16.
__device__ inline void stage16(const __bf16* g, __bf16* l) {
    __builtin_amdgcn_global_load_lds(
        (const __attribute__((address_space(1))) void*)g,
        (__attribute__((address_space(3))) void*)l, 16, 0, 0);
}

// ---------------------------------------------------------------------------
// prep: fused cast_wo (blocks 0..1023) + KV projection (blocks 1024..3071).
// One launch instead of two: independent latency chains co-schedule on CUs
// instead of serializing at kernel boundaries.
// KV tile layouts for LDS staging in attention:
//   kh: per 64-row tile, element (t,d) at col chunk (d>>3)^(t&7)  [rows t].
//   vh: V TRANSPOSED per tile: [d=64 rows][t=64 cols], element (d,t) at
//       col chunk (t>>3)^(d&7). Both 8 KB contiguous per 64-kv tile.
// Both swizzled tiles assembled in LDS, then written coalesced 16B.
__global__ __launch_bounds__(256) void prep_kernel(const float* __restrict__ kv,
                                                   const float* __restrict__ wk,
                                                   const float* __restrict__ bk,
                                                   const float* __restrict__ wv,
                                                   const float* __restrict__ bv,
                                                   const float* __restrict__ wo,
                                                   __bf16* __restrict__ kh,
                                                   __bf16* __restrict__ vh,
                                                   __bf16* __restrict__ wo_bf) {
    __shared__ __bf16 ktile[64 * 72];       // rows t, swizzled d-cols
    __shared__ __bf16 vtile[64 * 72];       // rows d, swizzled t-cols

    if (blockIdx.x < 1024) {                // ---- wo cast region ----
        int i = (blockIdx.x * 256 + threadIdx.x) * 4;
        float4 v = *(const float4*)(wo + i);
        wo_bf[i + 0] = (__bf16)v.x;
        wo_bf[i + 1] = (__bf16)v.y;
        wo_bf[i + 2] = (__bf16)v.z;
        wo_bf[i + 3] = (__bf16)v.w;
        return;
    }

    // ---- KV projection region ----
    const int bx = blockIdx.x - 1024;       // 2048 blocks
    const int sblk = bx & 31, h = (bx >> 5) & 15, b = bx >> 9;
    const int w = threadIdx.x >> 6, lane = threadIdx.x & 63;
    const int l15 = lane & 15, quad = lane >> 4;
    const int t_base = sblk * 64 + w * 16;

    const float* xrow = kv + ((size_t)b * SKV_ + t_base + l15) * E_ + h * D_ + quad * 8;
    bf16x8 a0 = cvt8(xrow);
    bf16x8 a1 = cvt8(xrow + 32);

    f32x4 acck[4] = {zero4(), zero4(), zero4(), zero4()};
    f32x4 accv[4] = {zero4(), zero4(), zero4(), zero4()};
#pragma unroll
    for (int nb = 0; nb < 4; ++nb) {
        const float* wkrow = wk + (size_t)h * D_ * D_ + (nb * 16 + l15) * D_ + quad * 8;
        const float* wvrow = wv + (size_t)h * D_ * D_ + (nb * 16 + l15) * D_ + quad * 8;
        bf16x8 bk0 = cvt8(wkrow);
        bf16x8 bk1 = cvt8(wkrow + 32);
        bf16x8 bv0 = cvt8(wvrow);
        bf16x8 bv1 = cvt8(wvrow + 32);
        acck[nb] = MFMA16(a0, bk0, acck[nb]);
        acck[nb] = MFMA16(a1, bk1, acck[nb]);
        accv[nb] = MFMA16(a0, bv0, accv[nb]);
        accv[nb] = MFMA16(a1, bv1, accv[nb]);
    }

#pragma unroll
    for (int nb = 0; nb < 4; ++nb) {
        const int col = nb * 16 + l15;  // head-dim d
        const float biask = bk[h * D_ + col];
        const float biasv = bv[h * D_ + col];
#pragma unroll
        for (int r = 0; r < 4; ++r) {
            const int row = quad * 4 + r;        // t within wave's 16-row slab
            const int tl = w * 16 + row;         // tile-local t
            // K: swizzle col chunk by t&7 (== row&7 since w*16 = 0 mod 8)
            const int kcol = (((col >> 3) ^ (row & 7)) << 3) | (col & 7);
            ktile[tl * 72 + kcol] = (__bf16)(acck[nb][r] + biask);
            // V^T: row d=col, col t=tl; chunk swizzled by d&7.
            const int vcol = (((tl >> 3) ^ (col & 7)) << 3) | (tl & 7);
            vtile[col * 72 + vcol] = (__bf16)(accv[nb][r] + biasv);
        }
    }
    __syncthreads();

    const int bh = b * H_ + h;
    __bf16* kbase = kh + ((size_t)bh * SKV_ + sblk * 64) * D_;
    __bf16* vbase = vh + (((size_t)bh * (SKV_ / 64) + sblk) * 64) * 64;
    const int tid = threadIdx.x;
#pragma unroll
    for (int i = 0; i < 2; ++i) {
        const int seg = i * 256 + tid;
        const int row = seg >> 3, sg = seg & 7;
        bf16x8 kv8 = *(const bf16x8*)&ktile[row * 72 + sg * 8];
        *(bf16x8*)&kbase[(size_t)row * D_ + sg * 8] = kv8;
        bf16x8 vv8 = *(const bf16x8*)&vtile[row * 72 + sg * 8];
        *(bf16x8*)&vbase[(size_t)row * 64 + sg * 8] = vv8;
    }
}

// ---------------------------------------------------------------------------
// Attention v9 = R1-best flash attention + FUSED Q-projection prologue.
//   Prologue (once per block, amortized over 32 KV tiles): each wave projects
//   its 64 q-rows with wq (identical MFMA code to old proj_q), transposes
//   through its private t_lds tile (same-wave readback, no barrier) into the
//   aq B-fragments. Removes the 16 MB qh write + 16 MB read and one launch.
//   Main loop: S^T = K·Q^T (C col = q = lane&15); P^T = exp2(S^T) feeds PV
//   register-direct at K=32 (slot-permuted, matches V^T LDS layout);
//   row sums via ones-MFMA. K/V 64x64 tiles double-buffered via
//   global_load_lds, 1 barrier/tile.
// Grid 1-D 512: f = tq*64 + g, g=b*16+h -> all tiles of one (b,h) on one XCD.
__global__ __launch_bounds__(256, 2) void attn_kernel(const float* __restrict__ q,
                                                      const float* __restrict__ wq,
                                                      const float* __restrict__ bq,
                                                      const __bf16* __restrict__ kh,
                                                      const __bf16* __restrict__ vh,
                                                      __bf16* __restrict__ ctx) {
    __shared__ __bf16 k_lds[2][4096];       // 64 t-rows x 64 d (swizzled)
    __shared__ __bf16 v_lds[2][4096];       // 64 d-rows x 64 t (swizzled)
    __shared__ __bf16 t_lds[4][16][72];     // per-wave transpose (prologue+epilogue)

    const int w = threadIdx.x >> 6, lane = threadIdx.x & 63;
    const int l15 = lane & 15, quad = lane >> 4;
    const int f = blockIdx.x;
    const int g = f & 63, tq = f >> 6;
    const int b = g >> 4, h = g & 15;
    const int bh = b * H_ + h;
    const int s_base = tq * 256 + w * 64;
    const int sw8 = (l15 & 7) << 3;

    // ---- fused Q projection prologue ----
    bf16x8 aq[4][2];
    {
        __bf16* twp = &t_lds[w][0][0];
        bf16x8 bw[4][2];
#pragma unroll
        for (int nb = 0; nb < 4; ++nb) {
            const float* wrow = wq + (size_t)h * D_ * D_ + (nb * 16 + l15) * D_ + quad * 8;
            bw[nb][0] = cvt8(wrow);
            bw[nb][1] = cvt8(wrow + 32);
        }
#pragma unroll
        for (int qt = 0; qt < 4; ++qt) {
            const float* qrow =
                q + ((size_t)b * SQ_ + s_base + qt * 16 + l15) * E_ + h * D_ + quad * 8;
            bf16x8 a0 = cvt8(qrow);
            bf16x8 a1 = cvt8(qrow + 32);
            f32x4 acc[4] = {zero4(), zero4(), zero4(), zero4()};
#pragma unroll
            for (int nb = 0; nb < 4; ++nb) {
                acc[nb] = MFMA16(a0, bw[nb][0], acc[nb]);
                acc[nb] = MFMA16(a1, bw[nb][1], acc[nb]);
            }
            // C layout: row s = quad*4+r, col d = nb*16+l15 -> transpose via LDS
#pragma unroll
            for (int nb = 0; nb < 4; ++nb) {
                const int col = nb * 16 + l15;
                const float bias = bq[h * D_ + col];
#pragma unroll
                for (int r = 0; r < 4; ++r)
                    twp[(quad * 4 + r) * 72 + col] = (__bf16)((acc[nb][r] + bias) * QSCALE);
            }
            // same-wave readback: lane l15 = q-row, slot = d = quad*8+j
            aq[qt][0] = *(const bf16x8*)&twp[l15 * 72 + quad * 8];
            aq[qt][1] = *(const bf16x8*)&twp[l15 * 72 + 32 + quad * 8];
        }
    }

    const __bf16 one_bf = (__bf16)1.0f;
    bf16x8 ones;
#pragma unroll
    for (int j = 0; j < 8; ++j) ones[j] = one_bf;

    f32x4 oT[4][4];   // [qt][d-block], C-layout: col=q=lane&15, row=d=quad*4+r
    f32x4 lacc[4];    // row-sum accumulator per qt; all rows identical
#pragma unroll
    for (int qt = 0; qt < 4; ++qt) {
        lacc[qt] = zero4();
#pragma unroll
        for (int db = 0; db < 4; ++db) oT[qt][db] = zero4();
    }

    const __bf16* kt = kh + (size_t)bh * SKV_ * D_;
    const __bf16* vt = vh + (size_t)bh * SKV_ * D_;

    auto stage = [&](int buf, int it) {
#pragma unroll
        for (int c2 = 0; c2 < 2; ++c2) {
            const int c = w + c2 * 4;
            stage16(kt + (size_t)it * 4096 + c * 512 + lane * 8, &k_lds[buf][c * 512]);
            stage16(vt + (size_t)it * 4096 + c * 512 + lane * 8, &v_lds[buf][c * 512]);
        }
    };

    stage(0, 0);
    __syncthreads();

    for (int it = 0; it < SKV_ / 64; ++it) {
        const int cur = it & 1;
        if (it + 1 < SKV_ / 64) stage(cur ^ 1, it + 1);

        // K fragments (A-operand of S^T): lane = t, k = d = quad*8+j
        bf16x8 kf0[4], kf1[4];
#pragma unroll
        for (int nb = 0; nb < 4; ++nb) {
            const __bf16* kr = &k_lds[cur][(nb * 16 + l15) * 64];
            kf0[nb] = *(const bf16x8*)&kr[(quad << 3) ^ sw8];
            kf1[nb] = *(const bf16x8*)&kr[((quad + 4) << 3) ^ sw8];
        }
        // V^T fragments (A-operand of PV, K=32 permuted-slot layout):
        // lane = d; slot(quad,j) = t = 32a + (j>=4)*16 + quad*4 + (j&3)
        bf16x8 vtf[4][2];
#pragma unroll
        for (int db = 0; db < 4; ++db) {
            const __bf16* vr = &v_lds[cur][(db * 16 + l15) * 64];
#pragma unroll
            for (int a = 0; a < 2; ++a) {
                const int c_lo = a * 4 + (quad >> 1);
                const int lo_off = (((c_lo ^ (l15 & 7)) << 3) | ((quad & 1) * 4));
                const int hi_off = ((((c_lo + 2) ^ (l15 & 7)) << 3) | ((quad & 1) * 4));
                union { bf16x8 v8; bf16x4 h2[2]; } u;
                u.h2[0] = *(const bf16x4*)&vr[lo_off];
                u.h2[1] = *(const bf16x4*)&vr[hi_off];
                vtf[db][a] = u.v8;
            }
        }
        // per q-tile: S^T -> exp -> PV (register-direct, K=32)
#pragma unroll
        for (int qt = 0; qt < 4; ++qt) {
            f32x4 s[4] = {zero4(), zero4(), zero4(), zero4()};
#pragma unroll
            for (int nb = 0; nb < 4; ++nb) {
                s[nb] = MFMA16(kf0[nb], aq[qt][0], s[nb]);
                s[nb] = MFMA16(kf1[nb], aq[qt][1], s[nb]);
            }
            // pack P^T into two K=32 B-fragments (slot-permuted, matches vtf)
            bf16x8 pb[2];
#pragma unroll
            for (int a = 0; a < 2; ++a) {
#pragma unroll
                for (int hf = 0; hf < 2; ++hf) {
                    const int nb = a * 2 + hf;
                    pb[a][hf * 4 + 0] = (__bf16)__builtin_amdgcn_exp2f(s[nb][0]);
                    pb[a][hf * 4 + 1] = (__bf16)__builtin_amdgcn_exp2f(s[nb][1]);
                    pb[a][hf * 4 + 2] = (__bf16)__builtin_amdgcn_exp2f(s[nb][2]);
                    pb[a][hf * 4 + 3] = (__bf16)__builtin_amdgcn_exp2f(s[nb][3]);
                }
            }
            // row sums via ones-MFMA: lacc cols=q, fully reduced over 64 t
            lacc[qt] = MFMA16(ones, pb[0], lacc[qt]);
            lacc[qt] = MFMA16(ones, pb[1], lacc[qt]);
#pragma unroll
            for (int db = 0; db < 4; ++db)
#pragma unroll
                for (int a = 0; a < 2; ++a)
                    oT[qt][db] = MFMA16(vtf[db][a], pb[a], oT[qt][db]);
        }
        __syncthreads();
    }

    // epilogue: scale by 1/l (lacc[qt][0] = denominator for q=lane&15),
    // transpose via LDS, store
#pragma unroll
    for (int qt = 0; qt < 4; ++qt) {
        const float inv = 1.f / lacc[qt][0];
#pragma unroll
        for (int db = 0; db < 4; ++db) {
#pragma unroll
            for (int r = 0; r < 4; ++r) {
                t_lds[w][l15][db * 16 + quad * 4 + r] = (__bf16)(oT[qt][db][r] * inv);
            }
        }
        // same-wave read-back (no barrier): 8 lanes per q-row, 16B stores
#pragma unroll
        for (int pp = 0; pp < 2; ++pp) {
            const int row = (lane >> 3) + pp * 8;
            bf16x8 vrow = *(const bf16x8*)&t_lds[w][row][(lane & 7) * 8];
            *(bf16x8*)&ctx[((size_t)b * SQ_ + s_base + qt * 16 + row) * E_ + h * D_ +
                           (lane & 7) * 8] = vrow;
        }
    }
}

// ---------------------------------------------------------------------------
// Output GEMM (m97 structure): out[m,n] = sum_k ctx[m,k]*wo[n,k] + bo[n]
// M=8192, N=1024, K=1024. 128x128 block tile, BK=64, 4 waves x 64x64,
// A/B staged via global_load_lds (16B) into double-buffered LDS (64 KB,
// 2 blocks/CU), ds_read_b128 fragments. Chunk-XOR swizzle applied on the
// GLOBAL source address (LDS dest stays linear), reads XOR back ->
// conflict-free. Grid 512: f = nblk*64 + mblk -> XCD = mblk%8.
__global__ __launch_bounds__(256, 2) void ogemm_kernel(const __bf16* __restrict__ ctx,
                                                       const __bf16* __restrict__ wo_bf,
                                                       const float* __restrict__ bo,
                                                       float* __restrict__ out) {
    __shared__ __bf16 a_lds[2][8192];   // [128 m][8 chunks of 8 k-elems] swz
    __shared__ __bf16 b_lds[2][8192];   // [128 n][...] swz

    const int w = threadIdx.x >> 6, lane = threadIdx.x & 63;
    const int l15 = lane & 15, quad = lane >> 4;
    const int f = blockIdx.x;
    const int mblk = f & 63, nblk = f >> 6;
    const int m0 = mblk * 128, n0 = nblk * 128;
    const int wm = (w >> 1) * 64, wn = (w & 1) * 64;

    f32x4 acc[4][4];
#pragma unroll
    for (int sub = 0; sub < 4; ++sub)
#pragma unroll
        for (int nb = 0; nb < 4; ++nb) acc[sub][nb] = zero4();

    // staging: chunk c = w*4+i covers rows c*8..c*8+7 (8 lanes/row, 16B each).
    // stored[r][col8] = global[r][col8 ^ (r&7)]  (source pre-swizzled).
    const int sr = lane >> 3, sc = lane & 7;
    auto stage = [&](int buf, int kk) {
#pragma unroll
        for (int i = 0; i < 4; ++i) {
            const int c = w * 4 + i;
            const int r = c * 8 + sr;
            const int col8 = sc ^ (r & 7);
            stage16(ctx + (size_t)(m0 + r) * E_ + kk + col8 * 8, &a_lds[buf][c * 512]);
            stage16(wo_bf + (size_t)(n0 + r) * E_ + kk + col8 * 8, &b_lds[buf][c * 512]);
        }
    };

    stage(0, 0);
    __syncthreads();

    for (int it = 0; it < E_ / 64; ++it) {
        const int cur = it & 1;
        if (it + 1 < E_ / 64) stage(cur ^ 1, (it + 1) * 64);

#pragma unroll
        for (int h = 0; h < 2; ++h) {           // two K=32 halves of BK=64
            bf16x8 af[4], bf[4];
            const int cq = ((h * 4 + quad) ^ (l15 & 7)) * 8;
#pragma unroll
            for (int sub = 0; sub < 4; ++sub)
                af[sub] = *(const bf16x8*)&a_lds[cur][(wm + sub * 16 + l15) * 64 + cq];
#pragma unroll
            for (int nb = 0; nb < 4; ++nb)
                bf[nb] = *(const bf16x8*)&b_lds[cur][(wn + nb * 16 + l15) * 64 + cq];
#pragma unroll
            for (int nb = 0; nb < 4; ++nb)
#pragma unroll
                for (int sub = 0; sub < 4; ++sub)
                    acc[sub][nb] = MFMA16(af[sub], bf[nb], acc[sub][nb]);
        }
        __syncthreads();
    }

#pragma unroll
    for (int sub = 0; sub < 4; ++sub) {
#pragma unroll
        for (int nb = 0; nb < 4; ++nb) {
            const int col = n0 + wn + nb * 16 + l15;
            const float bias = bo[col];
#pragma unroll
            for (int r = 0; r < 4; ++r) {
                const int row = m0 + wm + sub * 16 + quad * 4 + r;
                out[(size_t)row * E_ + col] = acc[sub][nb][r] + bias;
            }
        }
    }
}

// ---------------------------------------------------------------------------
extern "C" void kernel_launch(void* const* d_in, const int* in_sizes, int n_in,
                              void* d_out, int out_size, void* d_ws, size_t ws_size,
                              hipStream_t stream) {
    const float* query = (const float*)d_in[0];
    const float* key_value = (const float*)d_in[1];
    const float* wq = (const float*)d_in[2];
    const float* bq = (const float*)d_in[3];
    const float* wk = (const float*)d_in[4];
    const float* bk = (const float*)d_in[5];
    const float* wv = (const float*)d_in[6];
    const float* bv = (const float*)d_in[7];
    const float* wo = (const float*)d_in[8];
    const float* bo = (const float*)d_in[9];
    float* out = (float*)d_out;

    // workspace layout (needs 50 MB): kh | vh | ctx | wo_bf
    char* ws = (char*)d_ws;
    __bf16* kh = (__bf16*)(ws);                         // 16 MB swizzled K tiles
    __bf16* vh = (__bf16*)(ws + (16u << 20));           // 16 MB swizzled V^T tiles
    __bf16* ctxb = (__bf16*)(ws + (32u << 20));         // 16 MB [B,SQ,E]
    __bf16* wo_bf = (__bf16*)(ws + (48u << 20));        // 2 MB  [E,E]

    hipLaunchKernelGGL(prep_kernel, dim3(1024 + B_ * H_ * (SKV_ / 64)), dim3(256), 0, stream,
                       key_value, wk, bk, wv, bv, wo, kh, vh, wo_bf);
    hipLaunchKernelGGL(attn_kernel, dim3(B_ * H_ * (SQ_ / 256)), dim3(256), 0, stream,
                       query, wq, bq, kh, vh, ctxb);
    hipLaunchKernelGGL(ogemm_kernel, dim3((B_ * SQ_ / 128) * (E_ / 128)), dim3(256), 0, stream,
                       ctxb, wo_bf, bo, out);
}